// Round 5
// baseline (95.234 us; speedup 1.0000x reference)
//
#include <hip/hip_runtime.h>
#include <stdint.h>

#define NB 2
#define NS 2048
#define NHK 8
#define ND 128
#define NWIN 1024

using bf16x8 = __bf16 __attribute__((ext_vector_type(8)));
using f32x4  = float  __attribute__((ext_vector_type(4)));
using f32x2  = float  __attribute__((ext_vector_type(2)));
using f32x8  = float  __attribute__((ext_vector_type(8)));
using u16x8  = unsigned short __attribute__((ext_vector_type(8)));
using u32x4  = unsigned int   __attribute__((ext_vector_type(4)));

#define L2_10K (13.287712379549449f / 64.0f)  // log2(10000)/64
#define MASKV (-3.0e38f)

static __device__ __forceinline__ float ex2(float x) {
  return __builtin_amdgcn_exp2f(x);
}

static __device__ __forceinline__ unsigned short f2bf(float x) {
  unsigned int u = __builtin_bit_cast(unsigned int, x);
  u += 0x7FFFu + ((u >> 16) & 1u);
  return (unsigned short)(u >> 16);
}

static __device__ __forceinline__ unsigned int cvtpk(float lo, float hi) {
  unsigned int r;
  asm("v_cvt_pk_bf16_f32 %0, %1, %2" : "=v"(r) : "v"(lo), "v"(hi));
  return r;
}

static __device__ __forceinline__ void gll16(const void* g, void* l) {
  __builtin_amdgcn_global_load_lds(
      (const __attribute__((address_space(1))) void*)g,
      (__attribute__((address_space(3))) void*)l, 16, 0, 0);
}

#define MFMA16(a, b, c) __builtin_amdgcn_mfma_f32_16x16x32_bf16((a), (b), (c), 0, 0, 0)

// DPP row_ror reduction within 16-lane rows
#define ROR(x, N) __builtin_bit_cast(float, __builtin_amdgcn_mov_dpp( \
    __builtin_bit_cast(int, (x)), 0x120 + (N), 0xF, 0xF, false))

// ---------------- cos/sin table: tab[p][0..63]=cos, [64..127]=sin ----------------
__global__ __launch_bounds__(64) void build_tab(float* __restrict__ tab) {
  const int p = blockIdx.x, f = threadIdx.x;
  float s, c;
  __sincosf((float)p * ex2(-(float)f * L2_10K), &s, &c);
  tab[(size_t)p * 128 + f] = c;
  tab[(size_t)p * 128 + 64 + f] = s;
}

// ---------------- prepass: per-tile K (roped, swizzled) and V ([d][key] swz) images ----
__global__ __launch_bounds__(256) void prepass(
    const float* __restrict__ kin, const float* __restrict__ vin,
    const int* __restrict__ pos, const float* __restrict__ tab,
    unsigned short* __restrict__ kimg, unsigned short* __restrict__ vimg) {
  const int bid = blockIdx.x;
  const int ti = bid & 63, gidx = bid >> 6;
  const int hk = gidx & 7, b = gidx >> 3;
  const int t = threadIdx.x;

  unsigned short* kout = kimg + (size_t)bid * 4096;
#pragma unroll
  for (int uu = 0; uu < 2; ++uu) {
    const int u = t * 2 + uu;
    const int j = u >> 4;
    const int d0 = ((u & 15) << 3) ^ ((j & 7) << 3);  // u16 index
    const int tok = (b << 11) + (ti << 5) + j;
    const float* kp = kin + (size_t)tok * (NHK * ND) + hk * ND;
    f32x8 a = *(const f32x8*)(kp + d0);
    f32x8 p = *(const f32x8*)(kp + (d0 ^ 64));
    const float* tr = tab + (size_t)(pos[tok] & 2047) * 128 + (d0 & 63);
    f32x8 c8 = *(const f32x8*)tr;
    f32x8 s8 = *(const f32x8*)(tr + 64);
    u16x8 o;
#pragma unroll
    for (int i = 0; i < 8; ++i) {
      float val = (d0 < 64) ? (a[i] * c8[i] - p[i] * s8[i])
                            : (a[i] * c8[i] + p[i] * s8[i]);
      o[i] = f2bf(val);
    }
    *(u16x8*)(kout + (size_t)u * 8) = o;
  }

  unsigned short* vout = vimg + (size_t)bid * 4096;
  {
    const int d0 = (t >> 2) << 1;
    const int kp4 = t & 3;
    const int tok0 = (b << 11) + (ti << 5) + (kp4 << 3);
    const float* vp = vin + (size_t)tok0 * (NHK * ND) + hk * ND + d0;
    u16x8 lo, hi;
#pragma unroll
    for (int i = 0; i < 8; ++i) {
      f32x2 r = *(const f32x2*)(vp + (size_t)i * (NHK * ND));
      lo[i] = f2bf(r[0]);
      hi[i] = f2bf(r[1]);
    }
    const int sub = kp4 ^ ((d0 >> 1) & 3);
    *(u16x8*)(vout + d0 * 32 + sub * 8) = lo;
    *(u16x8*)(vout + (d0 + 1) * 32 + sub * 8) = hi;
  }
}

// ---------------- fused flash attention (skewed pipeline: PV(t-1) || QK(t)) -------
// 256 thr = 4 waves (one per g). Wave: 32 q-rows (2 halves of 16) x D=128.
// K double-buffered, V triple-buffered; stage via global_load_lds from images.
// Iter t: barrier -> stage(t+1) -> [PV(t-1) + QK(t)] MFMA cluster -> softmax(t).
template <bool PRE>
__global__ __launch_bounds__(256, 3) void attn_fwd(
    const float* __restrict__ qin, const float* __restrict__ kin,
    const float* __restrict__ vin, const int* __restrict__ pos,
    const char* __restrict__ kimg, const char* __restrict__ vimg,
    const float* __restrict__ tab, float* __restrict__ out) {
  __shared__ __align__(16) char Kb[2][8192];
  __shared__ __align__(16) char Vb[3][8192];

  const int B = blockIdx.x;
  // XCD swizzle: all 64 q-tiles of a (b,hk) group land on one XCD; heavy tiles first
  const int group = (B & 7) + ((B >> 9) << 3);
  const int qt = 63 - ((B >> 3) & 63);
  const int hk = group & 7, b = group >> 3;

  const int tid = threadIdx.x;
  const int w = tid >> 6, lane = tid & 63, h = lane >> 4, ln = lane & 15;
  const int g = w;
  const int q0b = qt << 5;
  int lo = q0b - (NWIN - 1);
  if (lo < 0) lo = 0;
  lo &= ~31;
  const int ti0 = lo >> 5;
  const int nt = (q0b >> 5) - ti0 + 1;

  const size_t gbase = (size_t)group * 64 * 8192;
  const char* kg = PRE ? kimg + gbase + (size_t)(w * 128 + lane) * 16 : nullptr;
  const char* vg = PRE ? vimg + gbase + (size_t)(w * 128 + lane) * 16 : nullptr;

  auto stage = [&](int ks, int vs, int ti) {
    if constexpr (PRE) {
      const char* ksrc = kg + (size_t)ti * 8192;
      const char* vsrc = vg + (size_t)ti * 8192;
      char* kd = &Kb[ks][w * 2048];
      char* vd = &Vb[vs][w * 2048];
      gll16(ksrc, kd);
      gll16(ksrc + 1024, kd + 1024);
      gll16(vsrc, vd);
      gll16(vsrc + 1024, vd + 1024);
    } else {
      const int j = tid >> 3;
      const int du = (tid & 7) << 4;
      const int tok = (b << 11) + (ti << 5) + j;
      const float* kp = kin + (size_t)tok * (NHK * ND) + hk * ND;
      const float pj = (float)pos[tok];
#pragma unroll
      for (int gq = 0; gq < 2; ++gq) {
        const int dd = du + gq * 8;
        f32x8 a = *(const f32x8*)(kp + dd);
        f32x8 p = *(const f32x8*)(kp + (dd ^ 64));
        u16x8 o;
#pragma unroll
        for (int i = 0; i < 8; ++i) {
          float s, c;
          __sincosf(pj * ex2(-(float)((dd & 63) + i) * L2_10K), &s, &c);
          float val = (dd < 64) ? (a[i] * c - p[i] * s) : (a[i] * c + p[i] * s);
          o[i] = f2bf(val);
        }
        *(u16x8*)(&Kb[ks][((j << 8) + (dd << 1)) ^ ((j & 7) << 4)]) = o;
      }
      const int d0 = (tid >> 2) << 1;
      const int kp4 = tid & 3;
      const float* vp = vin + (size_t)((b << 11) + (ti << 5) + (kp4 << 3)) * (NHK * ND) + hk * ND + d0;
      u16x8 lov, hiv;
#pragma unroll
      for (int i = 0; i < 8; ++i) {
        f32x2 r = *(const f32x2*)(vp + (size_t)i * (NHK * ND));
        lov[i] = f2bf(r[0]);
        hiv[i] = f2bf(r[1]);
      }
      const int sub = kp4 ^ ((d0 >> 1) & 3);
      unsigned short* vb16 = (unsigned short*)Vb[vs];
      *(u16x8*)(vb16 + d0 * 32 + sub * 8) = lov;
      *(u16x8*)(vb16 + (d0 + 1) * 32 + sub * 8) = hiv;
    }
  };

  // prologue: stage tile 0 into K slot 0 / V slot 0 (overlaps Q rope)
  stage(0, 0, ti0);

  // ---- Q fragments: rope + scale*log2e, bf16 (cos/sin from tab in PRE mode) ----
  const float QSC = 0.08838834764831845f * 1.4426950408889634f;
  bf16x8 qfr[2][4];
#pragma unroll
  for (int hf = 0; hf < 2; ++hf) {
    const int qrow = q0b + hf * 16 + ln;
    const size_t tokq = (size_t)(b << 11) + qrow;
    const float* qp = qin + tokq * 4096 + (hk * 4 + g) * 128;
    const int posq = pos[tokq] & 2047;
#pragma unroll
    for (int pp = 0; pp < 2; ++pp) {
      const int rr = (pp << 5) + (h << 3);  // frag c=pp covers dims rr..rr+7 (lo), c=2+pp hi
      f32x8 lo8 = *(const f32x8*)(qp + rr);
      f32x8 hi8 = *(const f32x8*)(qp + rr + 64);
      f32x8 cc, ss;
      if constexpr (PRE) {
        const float* tp = tab + (size_t)posq * 128 + rr;
        cc = *(const f32x8*)tp;
        ss = *(const f32x8*)(tp + 64);
      } else {
        const float pf = (float)posq;
#pragma unroll
        for (int i = 0; i < 8; ++i) {
          float s, c;
          __sincosf(pf * ex2(-(float)(rr + i) * L2_10K), &s, &c);
          cc[i] = c;
          ss[i] = s;
        }
      }
      u16x8 ulo, uhi;
#pragma unroll
      for (int i = 0; i < 8; ++i) {
        ulo[i] = f2bf((lo8[i] * cc[i] - hi8[i] * ss[i]) * QSC);
        uhi[i] = f2bf((hi8[i] * cc[i] + lo8[i] * ss[i]) * QSC);
      }
      qfr[hf][pp] = __builtin_bit_cast(bf16x8, ulo);
      qfr[hf][2 + pp] = __builtin_bit_cast(bf16x8, uhi);
    }
  }

  f32x4 Oc[2][8] = {};
  float msh[2] = {-1e30f, -1e30f};  // running max per q-row, replicated over h-groups
  float lsum[2] = {};               // per-lane partial sums
  bf16x8 pap0, pap1;                // previous tile's P fragments
  const int sw = (ln & 7) << 4;
  const int vsub = (h ^ ((ln >> 1) & 3)) << 4;
  int vsp = 2, vsc = 0, vsn = 1;    // V slot rotation: tile tau lives in slot tau%3

  for (int t = 0; t < nt; ++t) {
    asm volatile("s_waitcnt vmcnt(0)" ::: "memory");
    __syncthreads();  // tile-t data resident; all waves done with overwritten slots
    if (t + 1 < nt) stage((t + 1) & 1, vsn, ti0 + t + 1);

    const int j0 = (ti0 + t) << 5;
    const char* KB = Kb[t & 1];
    const char* VB = Vb[vsp];

    // ---- MFMA cluster: PV(t-1) then QK(t), back-to-back ----
    __builtin_amdgcn_s_setprio(1);
    if (t > 0) {
#pragma unroll
      for (int db = 0; db < 8; ++db) {
        const bf16x8 vv = *(const bf16x8*)(VB + (db << 10) + (ln << 6) + vsub);
        Oc[0][db] = MFMA16(pap0, vv, Oc[0][db]);
        Oc[1][db] = MFMA16(pap1, vv, Oc[1][db]);
      }
    }
    f32x4 sT[2][2] = {};  // [qh][ki]
#pragma unroll
    for (int c = 0; c < 4; ++c) {
      const bf16x8 k0 = *(const bf16x8*)(
          KB + (((ln << 8) + (c << 6) + (h << 4)) ^ sw));
      const bf16x8 k1 = *(const bf16x8*)(
          KB + ((((16 + ln) << 8) + (c << 6) + (h << 4)) ^ sw));
      sT[0][0] = MFMA16(k0, qfr[0][c], sT[0][0]);
      sT[0][1] = MFMA16(k1, qfr[0][c], sT[0][1]);
      sT[1][0] = MFMA16(k0, qfr[1][c], sT[1][0]);
      sT[1][1] = MFMA16(k1, qfr[1][c], sT[1][1]);
    }
    __builtin_amdgcn_s_setprio(0);

    // ---- mask only boundary tiles (wave-uniform branch) ----
    if ((j0 >= q0b) || (j0 < q0b - 992)) {
#pragma unroll
      for (int qh = 0; qh < 2; ++qh) {
        const int irow = q0b + qh * 16 + ln;
#pragma unroll
        for (int ki = 0; ki < 2; ++ki)
#pragma unroll
          for (int r = 0; r < 4; ++r) {
            const int j = j0 + ki * 16 + (h << 2) + r;
            if (!(j <= irow && irow - j < NWIN)) sT[qh][ki][r] = MASKV;
          }
      }
    }

    // ---- online softmax: deferred-max fast path (pure per-lane) ----
    float pm[2];
#pragma unroll
    for (int qh = 0; qh < 2; ++qh) {
      const f32x4 s0 = sT[qh][0], s1 = sT[qh][1];
      pm[qh] = fmaxf(fmaxf(fmaxf(s0[0], s0[1]), fmaxf(s0[2], s0[3])),
                     fmaxf(fmaxf(s1[0], s1[1]), fmaxf(s1[2], s1[3])));
    }
    const float ov = fmaxf(pm[0] - msh[0], pm[1] - msh[1]);
    if (__any(ov > 8.0f)) {  // slow path: true row max + rescale (Oc already has PV(t-1))
#pragma unroll
      for (int qh = 0; qh < 2; ++qh) {
        float M = pm[qh];
        M = fmaxf(M, __shfl_xor(M, 16));
        M = fmaxf(M, __shfl_xor(M, 32));
        const float mn = fmaxf(msh[qh], M);
        const float co = ex2(msh[qh] - mn);
        msh[qh] = mn;
        lsum[qh] *= co;
        float coO[4];
#pragma unroll
        for (int r = 0; r < 4; ++r) coO[r] = __shfl(co, (h << 2) + r);
#pragma unroll
        for (int db = 0; db < 8; ++db)
#pragma unroll
          for (int r = 0; r < 4; ++r) Oc[qh][db][r] *= coO[r];
      }
    }
#pragma unroll
    for (int qh = 0; qh < 2; ++qh) {
#pragma unroll
      for (int ki = 0; ki < 2; ++ki)
#pragma unroll
        for (int r = 0; r < 4; ++r)
          sT[qh][ki][r] = ex2(sT[qh][ki][r] - msh[qh]);
      lsum[qh] += ((sT[qh][0][0] + sT[qh][0][1]) + (sT[qh][0][2] + sT[qh][0][3])) +
                  ((sT[qh][1][0] + sT[qh][1][1]) + (sT[qh][1][2] + sT[qh][1][3]));
      unsigned int A = cvtpk(sT[qh][0][0], sT[qh][0][1]);
      unsigned int Bk = cvtpk(sT[qh][0][2], sT[qh][0][3]);
      unsigned int C = cvtpk(sT[qh][1][0], sT[qh][1][1]);
      unsigned int D = cvtpk(sT[qh][1][2], sT[qh][1][3]);
      asm volatile("v_permlane32_swap_b32 %0, %1" : "+v"(A), "+v"(C));
      asm volatile("v_permlane16_swap_b32 %0, %1" : "+v"(A), "+v"(C));
      asm volatile("v_permlane32_swap_b32 %0, %1" : "+v"(Bk), "+v"(D));
      asm volatile("v_permlane16_swap_b32 %0, %1" : "+v"(Bk), "+v"(D));
      u32x4 pk4 = {A, Bk, C, D};
      if (qh == 0) pap0 = __builtin_bit_cast(bf16x8, pk4);
      else         pap1 = __builtin_bit_cast(bf16x8, pk4);
    }

    const int tmp = vsp;  // rotate V slots
    vsp = vsc; vsc = vsn; vsn = tmp;
  }

  // ---- final PV for the last tile ----
  {
    const char* VB = Vb[vsp];
#pragma unroll
    for (int db = 0; db < 8; ++db) {
      const bf16x8 vv = *(const bf16x8*)(VB + (db << 10) + (ln << 6) + vsub);
      Oc[0][db] = MFMA16(pap0, vv, Oc[0][db]);
      Oc[1][db] = MFMA16(pap1, vv, Oc[1][db]);
    }
  }

  // ---- epilogue: full row-sum, redistribute, write ----
#pragma unroll
  for (int qh = 0; qh < 2; ++qh) {
    float ls = lsum[qh];
    ls += __shfl_xor(ls, 16);
    ls += __shfl_xor(ls, 32);
#pragma unroll
    for (int r = 0; r < 4; ++r) {
      const float rl = 1.0f / __shfl(ls, (h << 2) + r);
      const int irow = q0b + qh * 16 + (h << 2) + r;
      float* op = out + ((size_t)(b << 11) + irow) * 4096 + (hk * 4 + g) * 128 + ln;
#pragma unroll
      for (int db = 0; db < 8; ++db) op[db * 16] = Oc[qh][db][r] * rl;
    }
  }
}

extern "C" void kernel_launch(void* const* d_in, const int* in_sizes, int n_in,
                              void* d_out, int out_size, void* d_ws, size_t ws_size,
                              hipStream_t stream) {
  const float* q = (const float*)d_in[0];
  const float* k = (const float*)d_in[1];
  const float* v = (const float*)d_in[2];
  const int* pos = (const int*)d_in[3];
  float* out = (float*)d_out;

  const size_t TAB = (size_t)2048 * 128 * 4;        // 1MB cos/sin table
  const size_t KIMG = (size_t)16 * 64 * 8192;       // 8MB per image
  const size_t need = TAB + 2 * KIMG;

  if (ws_size >= need) {
    float* tab = (float*)d_ws;
    char* kimg = (char*)d_ws + TAB;
    char* vimg = kimg + KIMG;
    build_tab<<<2048, 64, 0, stream>>>(tab);
    prepass<<<1024, 256, 0, stream>>>(k, v, pos, tab,
                                      (unsigned short*)kimg, (unsigned short*)vimg);
    attn_fwd<true><<<1024, 256, 0, stream>>>(q, k, v, pos, kimg, vimg, tab, out);
  } else {
    attn_fwd<false><<<1024, 256, 0, stream>>>(q, k, v, pos, nullptr, nullptr, nullptr, out);
  }
}